// Round 13
// baseline (555.762 us; speedup 1.0000x reference)
//
#include <hip/hip_runtime.h>
#include <hip/hip_bf16.h>
#include <hip/hip_cooperative_groups.h>

namespace cg = cooperative_groups;

typedef float f32x4 __attribute__((ext_vector_type(4)));
typedef int v8i __attribute__((ext_vector_type(8)));

#define NB 8
#define ND 512
#define NT 2048
#define NCODES 4096
#define NM (NB * NT)
#define MARGIN_F 0.2f
#define ENC_STRIDE 320

// MX fragment image (Zq, Cq), fp8 e4m3:
//   tile (R_, K_) = 128 rows x 128 k = 16 KB at ((R_*4 + K_) * 16384)
//   fragment rg (0..7) = 16 rows x 128 k = 2048 B at rg*2048 within tile
//   lane l's 16 B at l*16 (+1024 for k-high half): row rg*16+(l&15), k (l>>4)*32 + j

union Smem {
    struct { float tile[128][65]; float redc[4][16]; } p;  // prep: 33,536 B
    struct { unsigned char As[16384]; unsigned char Bs[16384]; } g;  // gemm: 32,768 B
    float red[4];
};

static __device__ inline void async_copy16(const void* g, void* l) {
    __builtin_amdgcn_global_load_lds(
        (const __attribute__((address_space(1))) unsigned int*)g,
        (__attribute__((address_space(3))) unsigned int*)l, 16, 0, 0);
}

// ---- prep unit u: [0,1024) student tile; [1024,1280) codebook slice ----
static __device__ void prep_unit(int u, const float* __restrict__ sf, const float* __restrict__ cb,
                                 unsigned char* __restrict__ Zq, float* __restrict__ npart,
                                 unsigned char* __restrict__ Cq, float* __restrict__ cnorm,
                                 Smem* sm) {
    const int tid = threadIdx.x;  // 256
    const int wave = tid >> 6, lane = tid & 63, l15 = lane & 15, kq = lane >> 4;
    __syncthreads();  // protect smem reuse across units

    if (u < 1024) {
        const int t0 = (u & 31) * 64;
        const int d0 = ((u >> 5) & 3) * 128;
        const int b = u >> 7;
        const float* src = sf + (size_t)b * ND * NT;
#pragma unroll
        for (int it = 0; it < 8; it++) {
            int idx = it * 256 + tid;
            int d = idx >> 4, t4 = (idx & 15) * 4;
            float4 v = *(const float4*)(src + (size_t)(d0 + d) * NT + t0 + t4);  // coalesced
            sm->p.tile[d][t4] = v.x; sm->p.tile[d][t4 + 1] = v.y;
            sm->p.tile[d][t4 + 2] = v.z; sm->p.tile[d][t4 + 3] = v.w;
        }
        __syncthreads();
        const int m0 = b * NT + t0;
        {
            const int trow = wave * 16 + l15;
            unsigned char q[32];
#pragma unroll
            for (int j = 0; j < 32; j += 2) {
                float a = sm->p.tile[kq * 32 + j][trow];
                float c = sm->p.tile[kq * 32 + j + 1][trow];
                int p = __builtin_amdgcn_cvt_pk_fp8_f32(a, c, 0, false);
                q[j] = (unsigned char)(p & 0xFF);
                q[j + 1] = (unsigned char)((p >> 8) & 0xFF);
            }
            const int M_ = m0 >> 7, rg = ((m0 >> 4) & 7) + wave, K_ = d0 >> 7;
            char* base = (char*)Zq + ((size_t)((M_ * 4 + K_) * 8 + rg)) * 2048;
            *(uint4*)(base + lane * 16) = *(uint4*)&q[0];
            *(uint4*)(base + 1024 + lane * 16) = *(uint4*)&q[16];
        }
        // fp32 row-norm partial over this tile's 128 d's
        if (tid < 64) {
            float s = 0.0f;
#pragma unroll 16
            for (int d = 0; d < 128; d++) {
                float v = sm->p.tile[d][tid];
                s += v * v;
            }
            npart[(size_t)(d0 >> 7) * NM + m0 + tid] = s;
        }
    } else {
        const int r0 = (u - 1024) * 16;
        const int row = r0 + l15;
        const int K_ = wave;  // each wave: one 128-k quarter
        const float* src = cb + (size_t)row * ND + K_ * 128 + kq * 32;
        unsigned char q[32];
        float s = 0.0f;
#pragma unroll
        for (int j4 = 0; j4 < 8; j4++) {
            float4 v = *(const float4*)(src + j4 * 4);
            s += v.x * v.x + v.y * v.y + v.z * v.z + v.w * v.w;
            int p0 = __builtin_amdgcn_cvt_pk_fp8_f32(v.x, v.y, 0, false);
            int p1 = __builtin_amdgcn_cvt_pk_fp8_f32(v.z, v.w, 0, false);
            q[j4 * 4 + 0] = (unsigned char)(p0 & 0xFF);
            q[j4 * 4 + 1] = (unsigned char)((p0 >> 8) & 0xFF);
            q[j4 * 4 + 2] = (unsigned char)(p1 & 0xFF);
            q[j4 * 4 + 3] = (unsigned char)((p1 >> 8) & 0xFF);
        }
        const int N_ = r0 >> 7, rg = (r0 >> 4) & 7;
        char* base = (char*)Cq + ((size_t)((N_ * 4 + K_) * 8 + rg)) * 2048;
        *(uint4*)(base + lane * 16) = *(uint4*)&q[0];
        *(uint4*)(base + 1024 + lane * 16) = *(uint4*)&q[16];
        s += __shfl_xor(s, 16);
        s += __shfl_xor(s, 32);
        if (lane < 16) sm->p.redc[wave][l15] = s;
        __syncthreads();
        if (tid < 16) cnorm[r0 + tid] = sm->p.redc[0][tid] + sm->p.redc[1][tid] +
                                        sm->p.redc[2][tid] + sm->p.redc[3][tid];
    }
}

// ---- GEMM unit (M_, nq): R12 structure (proven ~53 µs) ----
static __device__ void gemm_unit(int M_, int nq, const unsigned char* __restrict__ Zq,
                                 const unsigned char* __restrict__ Cq,
                                 const float* __restrict__ cnorm, const int* __restrict__ teacher,
                                 float* __restrict__ negq, float* __restrict__ posq, Smem* sm) {
    const int m0 = M_ * 128;
    const int tid = threadIdx.x;
    const int wave = tid >> 6, lane = tid & 63;
    const int wr = wave >> 1, wc = wave & 1;
    const int l15 = lane & 15, quad = lane >> 4;

    const float INF = __builtin_inff();
    float minv[4][4], posv[4][4];
    int tch[4][4];
#pragma unroll
    for (int mi = 0; mi < 4; mi++)
#pragma unroll
        for (int r = 0; r < 4; r++) {
            minv[mi][r] = INF;
            posv[mi][r] = INF;
            tch[mi][r] = teacher[m0 + wr * 64 + mi * 16 + quad * 4 + r];
        }

    const char* gA0 = (const char*)Zq + (size_t)M_ * 4 * 16384 + wave * 4096 + lane * 16;
    char* lA = (char*)sm->g.As + wave * 4096;
    char* lB = (char*)sm->g.Bs + wave * 4096;

    for (int nt = 0; nt < 4; nt++) {
        const int N_ = nq * 4 + nt;
        const int n0 = N_ * 128;
        const char* gA = gA0;
        const char* gB = (const char*)Cq + (size_t)N_ * 4 * 16384 + wave * 4096 + lane * 16;
        f32x4 acc[4][4] = {};

        for (int kt = 0; kt < 4; kt++) {
#pragma unroll
            for (int i = 0; i < 4; i++) {
                async_copy16(gA + i * 1024, lA + i * 1024);
                async_copy16(gB + i * 1024, lB + i * 1024);
            }
            gA += 16384; gB += 16384;
            __syncthreads();

            v8i av[4], bv[4];
#pragma unroll
            for (int mi = 0; mi < 4; mi++) {
                int rg = wr * 4 + mi;
                union { uint4 q[2]; v8i v; } u;
                u.q[0] = *(const uint4*)(sm->g.As + rg * 2048 + lane * 16);
                u.q[1] = *(const uint4*)(sm->g.As + rg * 2048 + 1024 + lane * 16);
                av[mi] = u.v;
            }
#pragma unroll
            for (int ni = 0; ni < 4; ni++) {
                int rg = wc * 4 + ni;
                union { uint4 q[2]; v8i v; } u;
                u.q[0] = *(const uint4*)(sm->g.Bs + rg * 2048 + lane * 16);
                u.q[1] = *(const uint4*)(sm->g.Bs + rg * 2048 + 1024 + lane * 16);
                bv[ni] = u.v;
            }
#pragma unroll
            for (int mi = 0; mi < 4; mi++)
#pragma unroll
                for (int ni = 0; ni < 4; ni++)
                    acc[mi][ni] = __builtin_amdgcn_mfma_scale_f32_16x16x128_f8f6f4(
                        av[mi], bv[ni], acc[mi][ni], 0, 0,
                        0, 0x7F7F7F7F, 0, 0x7F7F7F7F);  // scales = 1.0 (e8m0 127)
            __syncthreads();
        }

        float cn[4]; int col[4];
#pragma unroll
        for (int ni = 0; ni < 4; ni++) {
            col[ni] = n0 + wc * 64 + ni * 16 + l15;
            cn[ni] = cnorm[col[ni]];
        }
#pragma unroll
        for (int mi = 0; mi < 4; mi++)
#pragma unroll
            for (int r = 0; r < 4; r++) {
                int t = tch[mi][r];
#pragma unroll
                for (int ni = 0; ni < 4; ni++) {
                    float val = fmaf(-2.0f, acc[mi][ni][r], cn[ni]);
                    bool ist = (col[ni] == t);
                    minv[mi][r] = fminf(minv[mi][r], ist ? INF : val);
                    posv[mi][r] = fminf(posv[mi][r], ist ? val : INF);
                }
            }
    }

    const int slot = nq * 2 + wc;  // 0..15
#pragma unroll
    for (int mi = 0; mi < 4; mi++)
#pragma unroll
        for (int r = 0; r < 4; r++) {
            float mn = minv[mi][r], ps = posv[mi][r];
#pragma unroll
            for (int off = 1; off < 16; off <<= 1) {
                mn = fminf(mn, __shfl_xor(mn, off));
                ps = fminf(ps, __shfl_xor(ps, off));
            }
            if (l15 == 0) {
                int m = m0 + wr * 64 + mi * 16 + quad * 4 + r;
                negq[(size_t)slot * NM + m] = mn;
                posq[(size_t)slot * NM + m] = ps;
            }
        }
}

// ---- reduce unit (64 of them): 16 slots -> masked triplet block sum ----
static __device__ void reduce_unit(int bid, const float* __restrict__ negq,
                                   const float* __restrict__ posq, const float* __restrict__ npart,
                                   const int* __restrict__ lengths, float* __restrict__ blocksums,
                                   Smem* sm) {
    const float INF = __builtin_inff();
    const int m = bid * 256 + threadIdx.x;
    float mn = INF, ps = INF;
#pragma unroll
    for (int s = 0; s < 16; s++) {
        mn = fminf(mn, negq[(size_t)s * NM + m]);  // coalesced
        ps = fminf(ps, posq[(size_t)s * NM + m]);
    }
    float zn = npart[m] + npart[NM + m] + npart[2 * NM + m] + npart[3 * NM + m];
    float negd = sqrtf(fmaxf(zn + mn, 1e-12f));
    float posd = sqrtf(fmaxf(zn + ps, 1e-12f));
    float tri = fmaxf(posd - negd + MARGIN_F, 0.0f);
    int b = m >> 11;
    int tt = m & (NT - 1);
    int flen = lengths[b] / ENC_STRIDE;
    float val = (tt < flen) ? tri : 0.0f;

#pragma unroll
    for (int off = 1; off < 64; off <<= 1) val += __shfl_xor(val, off);
    int lane = threadIdx.x & 63, w = threadIdx.x >> 6;
    if (lane == 0) sm->red[w] = val;
    __syncthreads();
    if (threadIdx.x == 0)
        blocksums[bid] = sm->red[0] + sm->red[1] + sm->red[2] + sm->red[3];
}

static __device__ void finalize_unit(const int* __restrict__ lengths,
                                     const float* __restrict__ blocksums,
                                     float* __restrict__ out) {
    if (threadIdx.x < 64) {
        float s = blocksums[threadIdx.x];
#pragma unroll
        for (int off = 1; off < 64; off <<= 1) s += __shfl_xor(s, off);
        if (threadIdx.x == 0) {
            float cnt = 0.0f;
            for (int b = 0; b < NB; b++) cnt += (float)(lengths[b] / ENC_STRIDE);
            out[0] = s / (cnt + 1e-8f);
        }
    }
}

// ---- single cooperative uber-kernel: prep -> GEMM -> reduce -> finalize ----
__global__ __launch_bounds__(256, 2) void uber(
    const float* __restrict__ sf, const float* __restrict__ cb,
    const int* __restrict__ teacher, const int* __restrict__ lengths,
    unsigned char* __restrict__ Zq, float* __restrict__ npart,
    unsigned char* __restrict__ Cq, float* __restrict__ cnorm,
    float* __restrict__ negq, float* __restrict__ posq,
    float* __restrict__ blocksums, float* __restrict__ out) {
    __shared__ Smem sm;
    cg::grid_group grid = cg::this_grid();

    for (unsigned u = blockIdx.x; u < 1280; u += gridDim.x)
        prep_unit((int)u, sf, cb, Zq, npart, Cq, cnorm, &sm);
    __threadfence();
    grid.sync();

    // block b -> units b, b+512: same M_ (512%128==0), same XCD (b%8) => L2 locality
    for (unsigned u = blockIdx.x; u < 1024; u += gridDim.x)
        gemm_unit((int)(u & 127), (int)(u >> 7), Zq, Cq, cnorm, teacher, negq, posq, &sm);
    __threadfence();
    grid.sync();

    if (blockIdx.x < 64)
        reduce_unit((int)blockIdx.x, negq, posq, npart, lengths, blocksums, &sm);
    __threadfence();
    grid.sync();

    if (blockIdx.x == 0) finalize_unit(lengths, blocksums, out);
}

// ---- fallback wrappers (proven 4-kernel path) ----
__global__ void k_prep(const float* sf, const float* cb, unsigned char* Zq, float* npart,
                       unsigned char* Cq, float* cnorm) {
    __shared__ Smem sm;
    prep_unit((int)blockIdx.x, sf, cb, Zq, npart, Cq, cnorm, &sm);
}
__global__ __launch_bounds__(256, 2) void k_gemm(const unsigned char* Zq, const unsigned char* Cq,
                                                 const float* cnorm, const int* teacher,
                                                 float* negq, float* posq) {
    __shared__ Smem sm;
    gemm_unit((int)blockIdx.x, (int)blockIdx.y, Zq, Cq, cnorm, teacher, negq, posq, &sm);
}
__global__ void k_reduce(const float* negq, const float* posq, const float* npart,
                         const int* lengths, float* blocksums) {
    __shared__ Smem sm;
    reduce_unit((int)blockIdx.x, negq, posq, npart, lengths, blocksums, &sm);
}
__global__ void k_final(const int* lengths, const float* blocksums, float* out) {
    finalize_unit(lengths, blocksums, out);
}

extern "C" void kernel_launch(void* const* d_in, const int* in_sizes, int n_in,
                              void* d_out, int out_size, void* d_ws, size_t ws_size,
                              hipStream_t stream) {
    const float* sf = (const float*)d_in[0];
    const int* teacher = (const int*)d_in[1];
    const float* cb = (const float*)d_in[2];
    const int* lengths = (const int*)d_in[3];

    char* ws = (char*)d_ws;
    unsigned char* Zq = (unsigned char*)(ws);                  //  8,388,608 B
    unsigned char* Cq = (unsigned char*)(ws + 8388608);        //  2,097,152 B
    float* cnorm = (float*)(ws + 10485760);                    //     16,384 B
    float* npart = (float*)(ws + 10502144);                    //    262,144 B (4 x NM)
    float* negq = (float*)(ws + 10764288);                     //  1,048,576 B (16 x NM)
    float* posq = (float*)(ws + 11812864);                     //  1,048,576 B
    float* blocksums = (float*)(ws + 12861440);                //        256 B
    float* outp = (float*)d_out;

    void* args[] = {(void*)&sf, (void*)&cb, (void*)&teacher, (void*)&lengths,
                    (void*)&Zq, (void*)&npart, (void*)&Cq, (void*)&cnorm,
                    (void*)&negq, (void*)&posq, (void*)&blocksums, (void*)&outp};
    hipError_t err = hipLaunchCooperativeKernel((const void*)uber, dim3(512), dim3(256),
                                                args, 0, stream);
    if (err != hipSuccess) {
        (void)hipGetLastError();  // clear sticky error, use proven 4-kernel path
        k_prep<<<1280, 256, 0, stream>>>(sf, cb, Zq, npart, Cq, cnorm);
        k_gemm<<<dim3(128, 8), 256, 0, stream>>>(Zq, Cq, cnorm, teacher, negq, posq);
        k_reduce<<<64, 256, 0, stream>>>(negq, posq, npart, lengths, blocksums);
        k_final<<<1, 64, 0, stream>>>(lengths, blocksums, outp);
    }
}

// Round 14
// 133.801 us; speedup vs baseline: 4.1537x; 4.1537x over previous
//
#include <hip/hip_runtime.h>
#include <hip/hip_bf16.h>

typedef float f32x4 __attribute__((ext_vector_type(4)));
typedef int v8i __attribute__((ext_vector_type(8)));

#define NB 8
#define ND 512
#define NT 2048
#define NCODES 4096
#define NM (NB * NT)
#define MARGIN_F 0.2f
#define ENC_STRIDE 320

// MX fragment image (Zq, Cq), fp8 e4m3:
//   tile (R_, K_) = 128 rows x 128 k = 16 KB at ((R_*4 + K_) * 16384)
//   fragment rg (0..7) = 16 rows x 128 k = 2048 B at rg*2048 within tile
//   bytes [0,1024): lane l's 16 B at l*16 = row rg*16+(l&15), k = (l>>4)*32 + 0..15
//   bytes [1024,2048): same lanes, k = (l>>4)*32 + 16..31

static __device__ inline void async_copy16(const void* g, void* l) {
    __builtin_amdgcn_global_load_lds(
        (const __attribute__((address_space(1))) unsigned int*)g,
        (__attribute__((address_space(3))) unsigned int*)l, 16, 0, 0);
}

// ---- kernel 1: fused prep. blocks [0,1024): student; [1024,1280): codebook ----
// student: fp32 (B,D,T) -> fp8 frag image Zq + fp32 row-norm partials npart[K_][m]
// block 1279 also zeroes the accum/ticket pair (stream-ordered before reduce_final).
__global__ void prep_fused(const float* __restrict__ sf, const float* __restrict__ cb,
                           unsigned char* __restrict__ Zq, float* __restrict__ npart,
                           unsigned char* __restrict__ Cq, float* __restrict__ cnorm,
                           float* __restrict__ accum, unsigned int* __restrict__ ticket) {
    __shared__ float tile[128][65];
    __shared__ float redc[4][16];
    const int tid = threadIdx.x;  // 256
    const int wave = tid >> 6, lane = tid & 63, l15 = lane & 15, kq = lane >> 4;

    if (blockIdx.x < 1024) {
        const int bx = blockIdx.x;
        const int t0 = (bx & 31) * 64;
        const int d0 = ((bx >> 5) & 3) * 128;
        const int b = bx >> 7;
        const float* src = sf + (size_t)b * ND * NT;
#pragma unroll
        for (int it = 0; it < 8; it++) {
            int idx = it * 256 + tid;
            int d = idx >> 4, t4 = (idx & 15) * 4;
            float4 v = *(const float4*)(src + (size_t)(d0 + d) * NT + t0 + t4);  // coalesced
            tile[d][t4] = v.x; tile[d][t4 + 1] = v.y; tile[d][t4 + 2] = v.z; tile[d][t4 + 3] = v.w;
        }
        __syncthreads();
        const int m0 = b * NT + t0;
        // fp8 fragment emit: wave w -> fragment rg0+w; lane: row w*16+l15, k kq*32+j
        {
            const int trow = wave * 16 + l15;
            unsigned char q[32];
#pragma unroll
            for (int j = 0; j < 32; j += 2) {
                float a = tile[kq * 32 + j][trow];
                float c = tile[kq * 32 + j + 1][trow];
                int p = __builtin_amdgcn_cvt_pk_fp8_f32(a, c, 0, false);
                q[j] = (unsigned char)(p & 0xFF);
                q[j + 1] = (unsigned char)((p >> 8) & 0xFF);
            }
            const int M_ = m0 >> 7, rg = ((m0 >> 4) & 7) + wave, K_ = d0 >> 7;
            char* base = (char*)Zq + ((size_t)((M_ * 4 + K_) * 8 + rg)) * 2048;
            *(uint4*)(base + lane * 16) = *(uint4*)&q[0];
            *(uint4*)(base + 1024 + lane * 16) = *(uint4*)&q[16];
        }
        // fp32 row-norm partial over this block's 128 d's (exact)
        if (tid < 64) {
            float s = 0.0f;
#pragma unroll 16
            for (int d = 0; d < 128; d++) {
                float v = tile[d][tid];
                s += v * v;
            }
            npart[(size_t)(d0 >> 7) * NM + m0 + tid] = s;
        }
    } else {
        if (blockIdx.x == 1279 && tid == 0) { *accum = 0.0f; *ticket = 0u; }
        const int r0 = (blockIdx.x - 1024) * 16;
        const int row = r0 + l15;
        const int K_ = wave;  // each wave handles one 128-k quarter
        const float* src = cb + (size_t)row * ND + K_ * 128 + kq * 32;
        unsigned char q[32];
        float s = 0.0f;
#pragma unroll
        for (int j4 = 0; j4 < 8; j4++) {
            float4 v = *(const float4*)(src + j4 * 4);
            s += v.x * v.x + v.y * v.y + v.z * v.z + v.w * v.w;
            int p0 = __builtin_amdgcn_cvt_pk_fp8_f32(v.x, v.y, 0, false);
            int p1 = __builtin_amdgcn_cvt_pk_fp8_f32(v.z, v.w, 0, false);
            q[j4 * 4 + 0] = (unsigned char)(p0 & 0xFF);
            q[j4 * 4 + 1] = (unsigned char)((p0 >> 8) & 0xFF);
            q[j4 * 4 + 2] = (unsigned char)(p1 & 0xFF);
            q[j4 * 4 + 3] = (unsigned char)((p1 >> 8) & 0xFF);
        }
        const int N_ = r0 >> 7, rg = (r0 >> 4) & 7;
        char* base = (char*)Cq + ((size_t)((N_ * 4 + K_) * 8 + rg)) * 2048;
        *(uint4*)(base + lane * 16) = *(uint4*)&q[0];
        *(uint4*)(base + 1024 + lane * 16) = *(uint4*)&q[16];
        s += __shfl_xor(s, 16);
        s += __shfl_xor(s, 32);
        if (lane < 16) redc[wave][l15] = s;
        __syncthreads();
        if (tid < 16) cnorm[r0 + tid] = redc[0][tid] + redc[1][tid] + redc[2][tid] + redc[3][tid];
    }
}

// ---- kernel 2: MX-fp8 GEMM (R12 verbatim — measured ~53 µs) ----
__global__ __launch_bounds__(256, 2) void triplet_main(
    const unsigned char* __restrict__ Zq, const unsigned char* __restrict__ Cq,
    const float* __restrict__ cnorm, const int* __restrict__ teacher,
    float* __restrict__ negq, float* __restrict__ posq) {
    __shared__ __align__(16) unsigned char As[16384];
    __shared__ __align__(16) unsigned char Bs[16384];

    const int M_ = blockIdx.x;   // x-major => XCD = M_ % 8: strip-local L2 reuse
    const int nq = blockIdx.y;   // 0..7
    const int m0 = M_ * 128;
    const int tid = threadIdx.x;
    const int wave = tid >> 6, lane = tid & 63;
    const int wr = wave >> 1, wc = wave & 1;
    const int l15 = lane & 15, quad = lane >> 4;

    const float INF = __builtin_inff();
    float minv[4][4], posv[4][4];
    int tch[4][4];
#pragma unroll
    for (int mi = 0; mi < 4; mi++)
#pragma unroll
        for (int r = 0; r < 4; r++) {
            minv[mi][r] = INF;
            posv[mi][r] = INF;
            tch[mi][r] = teacher[m0 + wr * 64 + mi * 16 + quad * 4 + r];
        }

    const char* gA0 = (const char*)Zq + (size_t)M_ * 4 * 16384 + wave * 4096 + lane * 16;
    char* lA = (char*)As + wave * 4096;
    char* lB = (char*)Bs + wave * 4096;

    for (int nt = 0; nt < 4; nt++) {
        const int N_ = nq * 4 + nt;
        const int n0 = N_ * 128;
        const char* gA = gA0;
        const char* gB = (const char*)Cq + (size_t)N_ * 4 * 16384 + wave * 4096 + lane * 16;
        f32x4 acc[4][4] = {};

        for (int kt = 0; kt < 4; kt++) {
#pragma unroll
            for (int i = 0; i < 4; i++) {
                async_copy16(gA + i * 1024, lA + i * 1024);
                async_copy16(gB + i * 1024, lB + i * 1024);
            }
            gA += 16384; gB += 16384;
            __syncthreads();

            v8i av[4], bv[4];
#pragma unroll
            for (int mi = 0; mi < 4; mi++) {
                int rg = wr * 4 + mi;
                union { uint4 q[2]; v8i v; } u;
                u.q[0] = *(const uint4*)(As + rg * 2048 + lane * 16);
                u.q[1] = *(const uint4*)(As + rg * 2048 + 1024 + lane * 16);
                av[mi] = u.v;
            }
#pragma unroll
            for (int ni = 0; ni < 4; ni++) {
                int rg = wc * 4 + ni;
                union { uint4 q[2]; v8i v; } u;
                u.q[0] = *(const uint4*)(Bs + rg * 2048 + lane * 16);
                u.q[1] = *(const uint4*)(Bs + rg * 2048 + 1024 + lane * 16);
                bv[ni] = u.v;
            }
#pragma unroll
            for (int mi = 0; mi < 4; mi++)
#pragma unroll
                for (int ni = 0; ni < 4; ni++)
                    acc[mi][ni] = __builtin_amdgcn_mfma_scale_f32_16x16x128_f8f6f4(
                        av[mi], bv[ni], acc[mi][ni], 0, 0,
                        0, 0x7F7F7F7F, 0, 0x7F7F7F7F);  // scales = 1.0 (e8m0 127)
            __syncthreads();
        }

        // fold: running fp32 min of (cnorm - 2*dot); teacher value captured separately
        float cn[4]; int col[4];
#pragma unroll
        for (int ni = 0; ni < 4; ni++) {
            col[ni] = n0 + wc * 64 + ni * 16 + l15;
            cn[ni] = cnorm[col[ni]];
        }
#pragma unroll
        for (int mi = 0; mi < 4; mi++)
#pragma unroll
            for (int r = 0; r < 4; r++) {
                int t = tch[mi][r];
#pragma unroll
                for (int ni = 0; ni < 4; ni++) {
                    float val = fmaf(-2.0f, acc[mi][ni][r], cn[ni]);
                    bool ist = (col[ni] == t);
                    minv[mi][r] = fminf(minv[mi][r], ist ? INF : val);
                    posv[mi][r] = fminf(posv[mi][r], ist ? val : INF);
                }
            }
    }

    const int slot = nq * 2 + wc;  // 0..15
#pragma unroll
    for (int mi = 0; mi < 4; mi++)
#pragma unroll
        for (int r = 0; r < 4; r++) {
            float mn = minv[mi][r], ps = posv[mi][r];
#pragma unroll
            for (int off = 1; off < 16; off <<= 1) {
                mn = fminf(mn, __shfl_xor(mn, off));
                ps = fminf(ps, __shfl_xor(ps, off));
            }
            if (l15 == 0) {
                int m = m0 + wr * 64 + mi * 16 + quad * 4 + r;
                negq[(size_t)slot * NM + m] = mn;
                posq[(size_t)slot * NM + m] = ps;
            }
        }
}

// ---- kernel 3: per-row reduce over 16 slots + ticketed finalize (64 blocks only) ----
__global__ void reduce_final(const float* __restrict__ negq, const float* __restrict__ posq,
                             const float* __restrict__ npart, const int* __restrict__ lengths,
                             float* __restrict__ accum, unsigned int* __restrict__ ticket,
                             float* __restrict__ out) {
    const float INF = __builtin_inff();
    const int m = blockIdx.x * 256 + threadIdx.x;
    float mn = INF, ps = INF;
#pragma unroll
    for (int s = 0; s < 16; s++) {
        mn = fminf(mn, negq[(size_t)s * NM + m]);  // coalesced
        ps = fminf(ps, posq[(size_t)s * NM + m]);
    }
    float zn = npart[m] + npart[NM + m] + npart[2 * NM + m] + npart[3 * NM + m];
    float negd = sqrtf(fmaxf(zn + mn, 1e-12f));
    float posd = sqrtf(fmaxf(zn + ps, 1e-12f));
    float tri = fmaxf(posd - negd + MARGIN_F, 0.0f);
    int b = m >> 11;
    int tt = m & (NT - 1);
    int flen = lengths[b] / ENC_STRIDE;
    float val = (tt < flen) ? tri : 0.0f;

    __shared__ float red[4];
#pragma unroll
    for (int off = 1; off < 64; off <<= 1) val += __shfl_xor(val, off);
    int lane = threadIdx.x & 63, w = threadIdx.x >> 6;
    if (lane == 0) red[w] = val;
    __syncthreads();
    if (threadIdx.x == 0) {
        // 64 blocks x 2 same-address atomics: negligible contention (R6's failure was 4096)
        atomicAdd(accum, red[0] + red[1] + red[2] + red[3]);
        __threadfence();
        unsigned int old = atomicAdd(ticket, 1u);
        if (old == 63u) {  // last block: all adds are visible
            float total = atomicAdd(accum, 0.0f);
            float cnt = 0.0f;
            for (int bb = 0; bb < NB; bb++) cnt += (float)(lengths[bb] / ENC_STRIDE);
            out[0] = total / (cnt + 1e-8f);
        }
    }
}

extern "C" void kernel_launch(void* const* d_in, const int* in_sizes, int n_in,
                              void* d_out, int out_size, void* d_ws, size_t ws_size,
                              hipStream_t stream) {
    const float* sf = (const float*)d_in[0];
    const int* teacher = (const int*)d_in[1];
    const float* cb = (const float*)d_in[2];
    const int* lengths = (const int*)d_in[3];

    char* ws = (char*)d_ws;
    unsigned char* Zq = (unsigned char*)(ws);                  //  8,388,608 B
    unsigned char* Cq = (unsigned char*)(ws + 8388608);        //  2,097,152 B
    float* cnorm = (float*)(ws + 10485760);                    //     16,384 B
    float* npart = (float*)(ws + 10502144);                    //    262,144 B (4 x NM)
    float* negq = (float*)(ws + 10764288);                     //  1,048,576 B (16 x NM)
    float* posq = (float*)(ws + 11812864);                     //  1,048,576 B
    float* accum = (float*)(ws + 12861440);                    //          4 B
    unsigned int* ticket = (unsigned int*)(ws + 12861444);     //          4 B

    prep_fused<<<1280, 256, 0, stream>>>(sf, cb, Zq, npart, Cq, cnorm, accum, ticket);
    triplet_main<<<dim3(128, 8), 256, 0, stream>>>(Zq, Cq, cnorm, teacher, negq, posq);
    reduce_final<<<64, 256, 0, stream>>>(negq, posq, npart, lengths, accum, ticket,
                                         (float*)d_out);
}